// Round 2
// baseline (7293.237 us; speedup 1.0000x reference)
//
#include <hip/hip_runtime.h>
#include <cstdint>
#include <cstddef>

#define NFILT 40
#define NBINS 257
#define HID   64
#define BB    64      // batch
#define TT    2000    // time
#define GATES 256     // 4*HID
#define MTOT  (BB*TT) // 128000 rows

// ---------- activations ----------
__device__ __forceinline__ float sigm(float x) {
  return 1.0f / (1.0f + __expf(-x));
}
__device__ __forceinline__ float tanh_(float x) {
  float e = __expf(-2.0f * fabsf(x));
  float r = (1.0f - e) / (1.0f + e);
  return copysignf(r, x);
}

// gate permutation: pre/W columns stored as g' = j*4 + q  (orig g = q*64 + j)
__device__ __forceinline__ int gperm(int gp) { return ((gp & 3) << 6) | (gp >> 2); }

// ---------- kernel 1: build fbank (40x257) + per-filter support bounds ----------
__global__ void k_fbank(const float* __restrict__ binpoints,
                        float* __restrict__ fbank,
                        int* __restrict__ lohi /*[2*NFILT]*/) {
  __shared__ float b[NFILT + 2];
  int tid = threadIdx.x;
  if (tid < NFILT + 2) b[tid] = binpoints[tid];
  __syncthreads();
  if (tid < NFILT) {
    if (tid == NFILT - 1) { lohi[tid] = 0; lohi[NFILT + tid] = 0; }
    else {
      int lo = (int)floorf(b[tid]);
      int hi = (int)floorf(b[tid + 2]);
      if (lo < 0) lo = 0;
      if (hi > NBINS) hi = NBINS;
      lohi[tid] = lo; lohi[NFILT + tid] = hi;
    }
  }
  for (int idx = tid; idx < NFILT * NBINS; idx += blockDim.x) {
    int f = idx / NBINS, i = idx - f * NBINS;
    float bj = b[f], bj1 = b[f + 1], bj2 = b[f + 2];
    float fb0 = floorf(bj), fb1 = floorf(bj1), fb2 = floorf(bj2);
    float fi = (float)i;
    bool rise = (fi >= fb0) && (fi < fb1);
    bool fall = (fi >= fb1) && (fi < fb2);
    float d1 = bj1 - bj;  d1 = (d1 > 0.f) ? d1 : 1.f;
    float d2 = bj2 - bj1; d2 = (d2 > 0.f) ? d2 : 1.f;
    float rv = (fi - bj)  / (d1 * d1);
    float fv = (bj2 - fi) / (d2 * d2);
    float v = fall ? fv : (rise ? rv : 0.f);
    if (f == NFILT - 1) v = 0.f;
    fbank[idx] = v;
  }
}

// ---------- kernel 2: featurize  h0[bt][f] = log(filt + 1e-10) ----------
__global__ __launch_bounds__(64) void k_feat(const float* __restrict__ x,
                                             const float* __restrict__ fbank,
                                             const int* __restrict__ lohi,
                                             float* __restrict__ h0) {
  int bt = blockIdx.x;
  __shared__ float xs[NBINS];
  const float* xr = x + (size_t)bt * NBINS;
  for (int i = threadIdx.x; i < NBINS; i += 64) xs[i] = xr[i];
  __syncthreads();
  int f = threadIdx.x;
  if (f < NFILT) {
    float acc = 0.f;
    int lo = lohi[f], hi = lohi[NFILT + f];
    for (int i = lo; i < hi; ++i) acc = fmaf(xs[i], fbank[f * NBINS + i], acc);
    float val = (f == 0) ? xs[0] : acc;
    h0[(size_t)bt * NFILT + f] = logf(val + 1e-10f);
  }
}

// ---------- kernel 3: fp32 GEMM, writes pre in permuted layout g'=j*4+q ----------
template <int K, int BK>
__global__ __launch_bounds__(256) void k_gemm(const float* __restrict__ Hm,   // [MTOT][K]
                                              const float* __restrict__ W,    // [2][256][K] (orig rows)
                                              const float* __restrict__ bih,  // [2][256]
                                              const float* __restrict__ bhh,  // [2][256]
                                              float* __restrict__ pre) {      // [2][MTOT][256] permuted
  constexpr int BM = 128, BN = 64;
  __shared__ float Hs[BK][BM + 4];
  __shared__ float Ws[BK][BN + 4];
  const int d  = blockIdx.z;
  const int m0 = blockIdx.x * BM;
  const int g0 = blockIdx.y * BN;   // in g'-space
  const int tid = threadIdx.x;
  const int tx = tid & 15, ty = tid >> 4;

  float acc[8][4];
#pragma unroll
  for (int r = 0; r < 8; ++r)
#pragma unroll
    for (int j = 0; j < 4; ++j) acc[r][j] = 0.f;

  for (int k0 = 0; k0 < K; k0 += BK) {
    constexpr int HL = BM * BK / 256;
#pragma unroll
    for (int i = 0; i < HL; ++i) {
      int flat = tid + i * 256;
      int r = flat / BK, kk = flat - r * BK;
      Hs[kk][r] = Hm[(size_t)(m0 + r) * K + k0 + kk];
    }
    constexpr int WL = BN * BK / 256;
#pragma unroll
    for (int i = 0; i < WL; ++i) {
      int flat = tid + i * 256;
      int r = flat / BK, kk = flat - r * BK;
      Ws[kk][r] = W[((size_t)d * GATES + gperm(g0 + r)) * K + k0 + kk];
    }
    __syncthreads();
#pragma unroll
    for (int kk = 0; kk < BK; ++kk) {
      const float4 wv  = *(const float4*)&Ws[kk][tx * 4];
      const float4 hv0 = *(const float4*)&Hs[kk][ty * 8];
      const float4 hv1 = *(const float4*)&Hs[kk][ty * 8 + 4];
      const float hr[8] = {hv0.x, hv0.y, hv0.z, hv0.w, hv1.x, hv1.y, hv1.z, hv1.w};
#pragma unroll
      for (int r = 0; r < 8; ++r) {
        acc[r][0] = fmaf(hr[r], wv.x, acc[r][0]);
        acc[r][1] = fmaf(hr[r], wv.y, acc[r][1]);
        acc[r][2] = fmaf(hr[r], wv.z, acc[r][2]);
        acc[r][3] = fmaf(hr[r], wv.w, acc[r][3]);
      }
    }
    __syncthreads();
  }

  const int gcol = g0 + tx * 4;   // g'-space columns
  float bsum[4];
#pragma unroll
  for (int i = 0; i < 4; ++i) {
    const int og = gperm(gcol + i);
    bsum[i] = bih[d * GATES + og] + bhh[d * GATES + og];
  }
#pragma unroll
  for (int r = 0; r < 8; ++r) {
    size_t m = (size_t)(m0 + ty * 8 + r);
    float4 o = {acc[r][0] + bsum[0], acc[r][1] + bsum[1], acc[r][2] + bsum[2], acc[r][3] + bsum[3]};
    *(float4*)&pre[((size_t)d * MTOT + m) * GATES + gcol] = o;
  }
}

// ---------- kernel 4: recurrent LSTM, ONE WAVE per (batch, dir) — no barriers ----------
__global__ __launch_bounds__(64, 1) void k_lstm1w(const float* __restrict__ pre, // [2][B*T][64][4] permuted
                                                  const float* __restrict__ whh, // [2][256][64] orig
                                                  float* __restrict__ hout,      // [B][T][128]
                                                  float* __restrict__ out,       // [B][128]
                                                  int final_layer) {
  const int b = blockIdx.x & (BB - 1);
  const int d = blockIdx.x >> 6;
  const int j = threadIdx.x;           // hidden unit owned by this lane
  __shared__ __align__(16) float h_s[HID];

  // lane j holds all 4 gate rows for unit j: orig rows q*64+j, 64 floats each
  float4 w[4][16];
#pragma unroll
  for (int q = 0; q < 4; ++q) {
    const float4* wr = (const float4*)(whh + ((size_t)d * GATES + q * HID + j) * HID);
#pragma unroll
    for (int kk = 0; kk < 16; ++kk) w[q][kk] = wr[kk];
  }

  h_s[j] = 0.f;
  float c = 0.f, sum = 0.f;
  __builtin_amdgcn_wave_barrier();

  const size_t base = ((size_t)d * BB + b) * (size_t)TT;
  const int t0 = d ? (TT - 1) : 0;
  const int dt = d ? -1 : 1;

  const float4* prow = (const float4*)pre;  // 64 float4 per row
  float4 pc = prow[(base + (size_t)t0) * 64 + j];
  float4 pn = prow[(base + (size_t)(t0 + dt)) * 64 + j];

  for (int t = 0; t < TT; ++t) {
    const int ta = t0 + dt * t;
    // prefetch 2 steps ahead; overreach stays inside the pre allocation (values unused)
    const float4 pn2 = prow[(base + (size_t)(ta + 2 * dt)) * 64 + j];

    float acc[4][4];
#pragma unroll
    for (int q = 0; q < 4; ++q) { acc[q][0] = acc[q][1] = acc[q][2] = acc[q][3] = 0.f; }
    const float4* h4 = (const float4*)h_s;
#pragma unroll
    for (int kk = 0; kk < 16; ++kk) {
      const float4 hv = h4[kk];   // same-address broadcast read, conflict-free
#pragma unroll
      for (int q = 0; q < 4; ++q) {
        acc[q][0] = fmaf(hv.x, w[q][kk].x, acc[q][0]);
        acc[q][1] = fmaf(hv.y, w[q][kk].y, acc[q][1]);
        acc[q][2] = fmaf(hv.z, w[q][kk].z, acc[q][2]);
        acc[q][3] = fmaf(hv.w, w[q][kk].w, acc[q][3]);
      }
    }
    const float zi = ((acc[0][0] + acc[0][1]) + (acc[0][2] + acc[0][3])) + pc.x;
    const float zf = ((acc[1][0] + acc[1][1]) + (acc[1][2] + acc[1][3])) + pc.y;
    const float zg = ((acc[2][0] + acc[2][1]) + (acc[2][2] + acc[2][3])) + pc.z;
    const float zo = ((acc[3][0] + acc[3][1]) + (acc[3][2] + acc[3][3])) + pc.w;

    const float ig = sigm(zi), fg = sigm(zf), gg = tanh_(zg), og = sigm(zo);
    c = fmaf(fg, c, ig * gg);
    const float hv = og * tanh_(c);

    __builtin_amdgcn_wave_barrier();   // keep write after this iter's reads
    h_s[j] = hv;                       // single-wave LDS is in-order: next iter's reads see it
    __builtin_amdgcn_wave_barrier();

    if (final_layer) sum += hv;
    else hout[((size_t)b * TT + ta) * (2 * HID) + d * HID + j] = hv;

    pc = pn; pn = pn2;
  }
  if (final_layer) out[b * (2 * HID) + d * HID + j] = sum * (1.0f / (float)TT);
}

// ---------- launch ----------
extern "C" void kernel_launch(void* const* d_in, const int* in_sizes, int n_in,
                              void* d_out, int out_size, void* d_ws, size_t ws_size,
                              hipStream_t stream) {
  const float* x         = (const float*)d_in[0];
  const float* binpoints = (const float*)d_in[1];
  const float* w_ih[3] = {(const float*)d_in[2], (const float*)d_in[6],  (const float*)d_in[10]};
  const float* w_hh[3] = {(const float*)d_in[3], (const float*)d_in[7],  (const float*)d_in[11]};
  const float* b_ih[3] = {(const float*)d_in[4], (const float*)d_in[8],  (const float*)d_in[12]};
  const float* b_hh[3] = {(const float*)d_in[5], (const float*)d_in[9],  (const float*)d_in[13]};
  float* out = (float*)d_out;

  // workspace layout (~349 MB):
  //   pre  : 2*MTOT*256 f32 = 262,144,000 B
  //   Hbuf : MTOT*128 f32   =  65,536,000 B
  //   h0   : MTOT*40 f32    =  20,480,000 B
  //   fbank: 40*257 f32, lohi: 80 i32
  float* pre   = (float*)d_ws;
  float* Hbuf  = pre  + (size_t)2 * MTOT * GATES;
  float* h0    = Hbuf + (size_t)MTOT * 128;
  float* fbank = h0   + (size_t)MTOT * NFILT;
  int*   lohi  = (int*)(fbank + NFILT * NBINS);

  k_fbank<<<1, 256, 0, stream>>>(binpoints, fbank, lohi);
  k_feat<<<MTOT, 64, 0, stream>>>(x, fbank, lohi, h0);

  // layer 0 (K=40)
  k_gemm<40, 40><<<dim3(MTOT / 128, GATES / 64, 2), 256, 0, stream>>>(h0, w_ih[0], b_ih[0], b_hh[0], pre);
  k_lstm1w<<<BB * 2, 64, 0, stream>>>(pre, w_hh[0], Hbuf, out, 0);

  // layer 1 (K=128)
  k_gemm<128, 32><<<dim3(MTOT / 128, GATES / 64, 2), 256, 0, stream>>>(Hbuf, w_ih[1], b_ih[1], b_hh[1], pre);
  k_lstm1w<<<BB * 2, 64, 0, stream>>>(pre, w_hh[1], Hbuf, out, 0);

  // layer 2 (K=128)
  k_gemm<128, 32><<<dim3(MTOT / 128, GATES / 64, 2), 256, 0, stream>>>(Hbuf, w_ih[2], b_ih[2], b_hh[2], pre);
  k_lstm1w<<<BB * 2, 64, 0, stream>>>(pre, w_hh[2], Hbuf, out, 1);
}

// Round 3
// 4952.238 us; speedup vs baseline: 1.4727x; 1.4727x over previous
//
#include <hip/hip_runtime.h>
#include <cstdint>
#include <cstddef>

#define NFILT 40
#define NBINS 257
#define HID   64
#define BB    64      // batch
#define TT    2000    // time
#define GATES 256     // 4*HID
#define MTOT  (BB*TT) // 128000 rows

// ---------- activations ----------
__device__ __forceinline__ float sigm(float x) {
  return 1.0f / (1.0f + __expf(-x));
}
__device__ __forceinline__ float tanh_(float x) {
  float e = __expf(-2.0f * fabsf(x));
  float r = (1.0f - e) / (1.0f + e);
  return copysignf(r, x);
}

// ---------- kernel 1: build fbank (40x257) + per-filter support bounds ----------
__global__ void k_fbank(const float* __restrict__ binpoints,
                        float* __restrict__ fbank,
                        int* __restrict__ lohi /*[2*NFILT]*/) {
  __shared__ float b[NFILT + 2];
  int tid = threadIdx.x;
  if (tid < NFILT + 2) b[tid] = binpoints[tid];
  __syncthreads();
  if (tid < NFILT) {
    if (tid == NFILT - 1) { lohi[tid] = 0; lohi[NFILT + tid] = 0; }
    else {
      int lo = (int)floorf(b[tid]);
      int hi = (int)floorf(b[tid + 2]);
      if (lo < 0) lo = 0;
      if (hi > NBINS) hi = NBINS;
      lohi[tid] = lo; lohi[NFILT + tid] = hi;
    }
  }
  for (int idx = tid; idx < NFILT * NBINS; idx += blockDim.x) {
    int f = idx / NBINS, i = idx - f * NBINS;
    float bj = b[f], bj1 = b[f + 1], bj2 = b[f + 2];
    float fb0 = floorf(bj), fb1 = floorf(bj1), fb2 = floorf(bj2);
    float fi = (float)i;
    bool rise = (fi >= fb0) && (fi < fb1);
    bool fall = (fi >= fb1) && (fi < fb2);
    float d1 = bj1 - bj;  d1 = (d1 > 0.f) ? d1 : 1.f;
    float d2 = bj2 - bj1; d2 = (d2 > 0.f) ? d2 : 1.f;
    float rv = (fi - bj)  / (d1 * d1);
    float fv = (bj2 - fi) / (d2 * d2);
    float v = fall ? fv : (rise ? rv : 0.f);
    if (f == NFILT - 1) v = 0.f;
    fbank[idx] = v;
  }
}

// ---------- kernel 2: featurize  h0[bt][f] = log(filt + 1e-10) ----------
__global__ __launch_bounds__(64) void k_feat(const float* __restrict__ x,
                                             const float* __restrict__ fbank,
                                             const int* __restrict__ lohi,
                                             float* __restrict__ h0) {
  int bt = blockIdx.x;
  __shared__ float xs[NBINS];
  const float* xr = x + (size_t)bt * NBINS;
  for (int i = threadIdx.x; i < NBINS; i += 64) xs[i] = xr[i];
  __syncthreads();
  int f = threadIdx.x;
  if (f < NFILT) {
    float acc = 0.f;
    int lo = lohi[f], hi = lohi[NFILT + f];
    for (int i = lo; i < hi; ++i) acc = fmaf(xs[i], fbank[f * NBINS + i], acc);
    float val = (f == 0) ? xs[0] : acc;
    h0[(size_t)bt * NFILT + f] = logf(val + 1e-10f);
  }
}

// ---------- kernel 3: fp32 GEMM  pre[d][m][g] = H[m][:]·W[d][g][:] + bih + bhh ----------
template <int K, int BK>
__global__ __launch_bounds__(256) void k_gemm(const float* __restrict__ Hm,   // [MTOT][K]
                                              const float* __restrict__ W,    // [2][256][K]
                                              const float* __restrict__ bih,  // [2][256]
                                              const float* __restrict__ bhh,  // [2][256]
                                              float* __restrict__ pre) {      // [2][MTOT][256]
  constexpr int BM = 128, BN = 64;
  __shared__ float Hs[BK][BM + 4];
  __shared__ float Ws[BK][BN + 4];
  const int d  = blockIdx.z;
  const int m0 = blockIdx.x * BM;
  const int g0 = blockIdx.y * BN;
  const int tid = threadIdx.x;
  const int tx = tid & 15, ty = tid >> 4;

  float acc[8][4];
#pragma unroll
  for (int r = 0; r < 8; ++r)
#pragma unroll
    for (int j = 0; j < 4; ++j) acc[r][j] = 0.f;

  for (int k0 = 0; k0 < K; k0 += BK) {
    constexpr int HL = BM * BK / 256;
#pragma unroll
    for (int i = 0; i < HL; ++i) {
      int flat = tid + i * 256;
      int r = flat / BK, kk = flat - r * BK;
      Hs[kk][r] = Hm[(size_t)(m0 + r) * K + k0 + kk];
    }
    constexpr int WL = BN * BK / 256;
#pragma unroll
    for (int i = 0; i < WL; ++i) {
      int flat = tid + i * 256;
      int r = flat / BK, kk = flat - r * BK;
      Ws[kk][r] = W[((size_t)d * GATES + g0 + r) * K + k0 + kk];
    }
    __syncthreads();
#pragma unroll
    for (int kk = 0; kk < BK; ++kk) {
      const float4 wv  = *(const float4*)&Ws[kk][tx * 4];
      const float4 hv0 = *(const float4*)&Hs[kk][ty * 8];
      const float4 hv1 = *(const float4*)&Hs[kk][ty * 8 + 4];
      const float hr[8] = {hv0.x, hv0.y, hv0.z, hv0.w, hv1.x, hv1.y, hv1.z, hv1.w};
#pragma unroll
      for (int r = 0; r < 8; ++r) {
        acc[r][0] = fmaf(hr[r], wv.x, acc[r][0]);
        acc[r][1] = fmaf(hr[r], wv.y, acc[r][1]);
        acc[r][2] = fmaf(hr[r], wv.z, acc[r][2]);
        acc[r][3] = fmaf(hr[r], wv.w, acc[r][3]);
      }
    }
    __syncthreads();
  }

  const int gcol = g0 + tx * 4;
  const float4 bi = *(const float4*)&bih[d * GATES + gcol];
  const float4 bh = *(const float4*)&bhh[d * GATES + gcol];
  const float bx = bi.x + bh.x, by = bi.y + bh.y, bz = bi.z + bh.z, bw = bi.w + bh.w;
#pragma unroll
  for (int r = 0; r < 8; ++r) {
    size_t m = (size_t)(m0 + ty * 8 + r);
    float4 o = {acc[r][0] + bx, acc[r][1] + by, acc[r][2] + bz, acc[r][3] + bw};
    *(float4*)&pre[((size_t)d * MTOT + m) * GATES + gcol] = o;
  }
}

// ---------- kernel 4: recurrent LSTM, 4 waves/(b,d), LDS spin sync (no s_barrier) ----------
// Thread g owns gate row g (orig order). Wave w = gate type. Each wave keeps a
// PRIVATE replica of h (h_s[w]) and of c/sum for its lane's unit, so the only
// cross-wave exchange is the pre-activation z through double-buffered zbuf.
// Spin-flag sync touches only lgkmcnt -> 4-deep global prefetch never drains.
__global__ __launch_bounds__(256, 1) void k_lstm4w(const float* __restrict__ pre, // [2][B*T][256]
                                                   const float* __restrict__ whh, // [2][256][64]
                                                   float* __restrict__ hout,      // [B][T][128]
                                                   float* __restrict__ out,       // [B][128]
                                                   int final_layer) {
  const int b = blockIdx.x, d = blockIdx.y;
  const int g = threadIdx.x;
  const int w = g >> 6;            // wave id == gate type
  const int j = g & 63;            // hidden unit
  __shared__ __align__(16) float h_s[4][HID];
  __shared__ float zbuf[2][GATES];
  __shared__ volatile int flags[2][4];

  float4 wv[16];                   // 64 VGPRs of weights: row g of whh[d]
  const float4* wr = (const float4*)(whh + ((size_t)d * GATES + g) * HID);
#pragma unroll
  for (int kk = 0; kk < 16; ++kk) wv[kk] = wr[kk];

  h_s[w][j] = 0.f;
  if (g < 8) flags[g >> 2][g & 3] = 0;
  float c = 0.f, sum = 0.f;
  __syncthreads();                 // one-time; no loads in flight yet

  const size_t base = ((size_t)d * BB + b) * (size_t)TT;
  const int t0 = d ? (TT - 1) : 0;
  const int dt = d ? -1 : 1;
  const float* pp = pre + (base + (size_t)t0) * GATES + g;
  const ptrdiff_t pstr = (ptrdiff_t)dt * GATES;

  float pf0 = pp[0], pf1 = pp[pstr], pf2 = pp[pstr * 2], pf3 = pp[pstr * 3];

#define LSTM_STEP(TK, PAR, PF)                                                 \
  do {                                                                         \
    float a0 = 0.f, a1 = 0.f, a2 = 0.f, a3 = 0.f;                              \
    const float4* h4 = (const float4*)&h_s[w][0];                              \
    _Pragma("unroll")                                                          \
    for (int kk = 0; kk < 16; ++kk) {                                          \
      const float4 hv = h4[kk];                                                \
      a0 = fmaf(hv.x, wv[kk].x, a0);                                           \
      a1 = fmaf(hv.y, wv[kk].y, a1);                                           \
      a2 = fmaf(hv.z, wv[kk].z, a2);                                           \
      a3 = fmaf(hv.w, wv[kk].w, a3);                                           \
    }                                                                          \
    const float z = ((a0 + a1) + (a2 + a3)) + (PF);                            \
    zbuf[PAR][g] = z;                                                          \
    asm volatile("s_waitcnt lgkmcnt(0)" ::: "memory");                         \
    if (j == 0) flags[PAR][w] = (TK) + 1;                                      \
    while (!__all((int)(flags[PAR][j & 3] >= (TK) + 1))) {}                    \
    asm volatile("" ::: "memory");                                             \
    const float zi = zbuf[PAR][j],           zf = zbuf[PAR][HID + j];          \
    const float zg = zbuf[PAR][2 * HID + j], zo = zbuf[PAR][3 * HID + j];      \
    const float ig = sigm(zi), fg = sigm(zf), gg = tanh_(zg), og = sigm(zo);   \
    c = fmaf(fg, c, ig * gg);                                                  \
    const float hv2 = og * tanh_(c);                                           \
    h_s[w][j] = hv2;                                                           \
    if (final_layer) sum += hv2;                                               \
    else if (w == 0)                                                           \
      hout[((size_t)b * TT + (size_t)(t0 + dt * (TK))) * (2 * HID) + d * HID + j] = hv2; \
  } while (0)

  for (int t = 0; t < TT; t += 4) {
    LSTM_STEP(t + 0, 0, pf0);
    { int ip = t + 4; if (ip >= TT) ip = 0; pf0 = pp[pstr * (ptrdiff_t)ip]; }
    LSTM_STEP(t + 1, 1, pf1);
    { int ip = t + 5; if (ip >= TT) ip = 0; pf1 = pp[pstr * (ptrdiff_t)ip]; }
    LSTM_STEP(t + 2, 0, pf2);
    { int ip = t + 6; if (ip >= TT) ip = 0; pf2 = pp[pstr * (ptrdiff_t)ip]; }
    LSTM_STEP(t + 3, 1, pf3);
    { int ip = t + 7; if (ip >= TT) ip = 0; pf3 = pp[pstr * (ptrdiff_t)ip]; }
  }
#undef LSTM_STEP

  if (final_layer && w == 0) out[b * (2 * HID) + d * HID + j] = sum * (1.0f / (float)TT);
}

// ---------- launch ----------
extern "C" void kernel_launch(void* const* d_in, const int* in_sizes, int n_in,
                              void* d_out, int out_size, void* d_ws, size_t ws_size,
                              hipStream_t stream) {
  const float* x         = (const float*)d_in[0];
  const float* binpoints = (const float*)d_in[1];
  const float* w_ih[3] = {(const float*)d_in[2], (const float*)d_in[6],  (const float*)d_in[10]};
  const float* w_hh[3] = {(const float*)d_in[3], (const float*)d_in[7],  (const float*)d_in[11]};
  const float* b_ih[3] = {(const float*)d_in[4], (const float*)d_in[8],  (const float*)d_in[12]};
  const float* b_hh[3] = {(const float*)d_in[5], (const float*)d_in[9],  (const float*)d_in[13]};
  float* out = (float*)d_out;

  // workspace layout (~349 MB):
  //   pre  : 2*MTOT*256 f32 = 262,144,000 B
  //   Hbuf : MTOT*128 f32   =  65,536,000 B
  //   h0   : MTOT*40 f32    =  20,480,000 B
  //   fbank: 40*257 f32, lohi: 80 i32
  float* pre   = (float*)d_ws;
  float* Hbuf  = pre  + (size_t)2 * MTOT * GATES;
  float* h0    = Hbuf + (size_t)MTOT * 128;
  float* fbank = h0   + (size_t)MTOT * NFILT;
  int*   lohi  = (int*)(fbank + NFILT * NBINS);

  k_fbank<<<1, 256, 0, stream>>>(binpoints, fbank, lohi);
  k_feat<<<MTOT, 64, 0, stream>>>(x, fbank, lohi, h0);

  // layer 0 (K=40)
  k_gemm<40, 40><<<dim3(MTOT / 128, GATES / 64, 2), 256, 0, stream>>>(h0, w_ih[0], b_ih[0], b_hh[0], pre);
  k_lstm4w<<<dim3(BB, 2), 256, 0, stream>>>(pre, w_hh[0], Hbuf, out, 0);

  // layer 1 (K=128)
  k_gemm<128, 32><<<dim3(MTOT / 128, GATES / 64, 2), 256, 0, stream>>>(Hbuf, w_ih[1], b_ih[1], b_hh[1], pre);
  k_lstm4w<<<dim3(BB, 2), 256, 0, stream>>>(pre, w_hh[1], Hbuf, out, 0);

  // layer 2 (K=128)
  k_gemm<128, 32><<<dim3(MTOT / 128, GATES / 64, 2), 256, 0, stream>>>(Hbuf, w_ih[2], b_ih[2], b_hh[2], pre);
  k_lstm4w<<<dim3(BB, 2), 256, 0, stream>>>(pre, w_hh[2], Hbuf, out, 1);
}

// Round 4
// 4077.242 us; speedup vs baseline: 1.7888x; 1.2146x over previous
//
#include <hip/hip_runtime.h>
#include <cstdint>
#include <cstddef>

#define NFILT 40
#define NBINS 257
#define HID   64
#define BB    64      // batch
#define TT    2000    // time
#define GATES 256     // 4*HID
#define MTOT  (BB*TT) // 128000 rows

// ---------- activations ----------
__device__ __forceinline__ float sigm(float x) {
  return 1.0f / (1.0f + __expf(-x));
}
__device__ __forceinline__ float tanh_(float x) {
  float e = __expf(-2.0f * fabsf(x));
  float r = (1.0f - e) / (1.0f + e);
  return copysignf(r, x);
}

// ---------- kernel 1: build fbank (40x257) + per-filter support bounds ----------
__global__ void k_fbank(const float* __restrict__ binpoints,
                        float* __restrict__ fbank,
                        int* __restrict__ lohi /*[2*NFILT]*/) {
  __shared__ float b[NFILT + 2];
  int tid = threadIdx.x;
  if (tid < NFILT + 2) b[tid] = binpoints[tid];
  __syncthreads();
  if (tid < NFILT) {
    if (tid == NFILT - 1) { lohi[tid] = 0; lohi[NFILT + tid] = 0; }
    else {
      int lo = (int)floorf(b[tid]);
      int hi = (int)floorf(b[tid + 2]);
      if (lo < 0) lo = 0;
      if (hi > NBINS) hi = NBINS;
      lohi[tid] = lo; lohi[NFILT + tid] = hi;
    }
  }
  for (int idx = tid; idx < NFILT * NBINS; idx += blockDim.x) {
    int f = idx / NBINS, i = idx - f * NBINS;
    float bj = b[f], bj1 = b[f + 1], bj2 = b[f + 2];
    float fb0 = floorf(bj), fb1 = floorf(bj1), fb2 = floorf(bj2);
    float fi = (float)i;
    bool rise = (fi >= fb0) && (fi < fb1);
    bool fall = (fi >= fb1) && (fi < fb2);
    float d1 = bj1 - bj;  d1 = (d1 > 0.f) ? d1 : 1.f;
    float d2 = bj2 - bj1; d2 = (d2 > 0.f) ? d2 : 1.f;
    float rv = (fi - bj)  / (d1 * d1);
    float fv = (bj2 - fi) / (d2 * d2);
    float v = fall ? fv : (rise ? rv : 0.f);
    if (f == NFILT - 1) v = 0.f;
    fbank[idx] = v;
  }
}

// ---------- kernel 2: featurize  h0[bt][f] = log(filt + 1e-10) ----------
__global__ __launch_bounds__(64) void k_feat(const float* __restrict__ x,
                                             const float* __restrict__ fbank,
                                             const int* __restrict__ lohi,
                                             float* __restrict__ h0) {
  int bt = blockIdx.x;
  __shared__ float xs[NBINS];
  const float* xr = x + (size_t)bt * NBINS;
  for (int i = threadIdx.x; i < NBINS; i += 64) xs[i] = xr[i];
  __syncthreads();
  int f = threadIdx.x;
  if (f < NFILT) {
    float acc = 0.f;
    int lo = lohi[f], hi = lohi[NFILT + f];
    for (int i = lo; i < hi; ++i) acc = fmaf(xs[i], fbank[f * NBINS + i], acc);
    float val = (f == 0) ? xs[0] : acc;
    h0[(size_t)bt * NFILT + f] = logf(val + 1e-10f);
  }
}

// ---------- kernel 3: fp32 GEMM  pre[d][m][g] = H[m][:]·W[d][g][:] + bih + bhh ----------
template <int K, int BK>
__global__ __launch_bounds__(256) void k_gemm(const float* __restrict__ Hm,   // [MTOT][K]
                                              const float* __restrict__ W,    // [2][256][K]
                                              const float* __restrict__ bih,  // [2][256]
                                              const float* __restrict__ bhh,  // [2][256]
                                              float* __restrict__ pre) {      // [2][MTOT][256]
  constexpr int BM = 128, BN = 64;
  __shared__ float Hs[BK][BM + 4];
  __shared__ float Ws[BK][BN + 4];
  const int d  = blockIdx.z;
  const int m0 = blockIdx.x * BM;
  const int g0 = blockIdx.y * BN;
  const int tid = threadIdx.x;
  const int tx = tid & 15, ty = tid >> 4;

  float acc[8][4];
#pragma unroll
  for (int r = 0; r < 8; ++r)
#pragma unroll
    for (int j = 0; j < 4; ++j) acc[r][j] = 0.f;

  for (int k0 = 0; k0 < K; k0 += BK) {
    constexpr int HL = BM * BK / 256;
#pragma unroll
    for (int i = 0; i < HL; ++i) {
      int flat = tid + i * 256;
      int r = flat / BK, kk = flat - r * BK;
      Hs[kk][r] = Hm[(size_t)(m0 + r) * K + k0 + kk];
    }
    constexpr int WL = BN * BK / 256;
#pragma unroll
    for (int i = 0; i < WL; ++i) {
      int flat = tid + i * 256;
      int r = flat / BK, kk = flat - r * BK;
      Ws[kk][r] = W[((size_t)d * GATES + g0 + r) * K + k0 + kk];
    }
    __syncthreads();
#pragma unroll
    for (int kk = 0; kk < BK; ++kk) {
      const float4 wv  = *(const float4*)&Ws[kk][tx * 4];
      const float4 hv0 = *(const float4*)&Hs[kk][ty * 8];
      const float4 hv1 = *(const float4*)&Hs[kk][ty * 8 + 4];
      const float hr[8] = {hv0.x, hv0.y, hv0.z, hv0.w, hv1.x, hv1.y, hv1.z, hv1.w};
#pragma unroll
      for (int r = 0; r < 8; ++r) {
        acc[r][0] = fmaf(hr[r], wv.x, acc[r][0]);
        acc[r][1] = fmaf(hr[r], wv.y, acc[r][1]);
        acc[r][2] = fmaf(hr[r], wv.z, acc[r][2]);
        acc[r][3] = fmaf(hr[r], wv.w, acc[r][3]);
      }
    }
    __syncthreads();
  }

  const int gcol = g0 + tx * 4;
  const float4 bi = *(const float4*)&bih[d * GATES + gcol];
  const float4 bh = *(const float4*)&bhh[d * GATES + gcol];
  const float bx = bi.x + bh.x, by = bi.y + bh.y, bz = bi.z + bh.z, bw = bi.w + bh.w;
#pragma unroll
  for (int r = 0; r < 8; ++r) {
    size_t m = (size_t)(m0 + ty * 8 + r);
    float4 o = {acc[r][0] + bx, acc[r][1] + by, acc[r][2] + bz, acc[r][3] + bw};
    *(float4*)&pre[((size_t)d * MTOT + m) * GATES + gcol] = o;
  }
}

// ---------- kernel 4: recurrent LSTM, 4 waves/(b,d), raw s_barrier (no vmcnt drain) ----------
// Thread g owns gate row g. Wave w = gate type; each wave keeps a PRIVATE replica
// of h, so the only cross-wave exchange is the ACTIVATED gate value through the
// parity-double-buffered abuf. Sync = inline-asm "s_waitcnt lgkmcnt(0); s_barrier":
// hardware s_barrier does not drain vmcnt, and since the barrier comes from asm the
// compiler never emits the vmcnt(0) drain -> 4-deep HBM prefetch stays in flight.
// Race-freedom of 1 barrier/step: a wave's lgkmcnt(0) before barrier t+1 proves its
// parity-p reads completed; the next write to parity p happens only after barrier t+1.
__global__ __launch_bounds__(256, 1) void k_lstm4w(const float* __restrict__ pre, // [2][B*T][256]
                                                   const float* __restrict__ whh, // [2][256][64]
                                                   float* __restrict__ hout,      // [B][T][128]
                                                   float* __restrict__ out,       // [B][128]
                                                   int final_layer) {
  const int b = blockIdx.x, d = blockIdx.y;
  const int g = threadIdx.x;
  const int w = g >> 6;            // wave id == gate type (0:i 1:f 2:g 3:o)
  const int j = g & 63;            // hidden unit
  __shared__ __align__(16) float h_s[4][HID];
  __shared__ float abuf[2][GATES];          // activated gate values

  float4 wv[16];                   // 64 VGPRs of weights: row g of whh[d]
  const float4* wr = (const float4*)(whh + ((size_t)d * GATES + g) * HID);
#pragma unroll
  for (int kk = 0; kk < 16; ++kk) wv[kk] = wr[kk];

  h_s[w][j] = 0.f;
  float c = 0.f, sum = 0.f;
  __syncthreads();                 // one-time (weight loads drained here, fine)

  const size_t base = ((size_t)d * BB + b) * (size_t)TT;
  const int t0 = d ? (TT - 1) : 0;
  const int dt = d ? -1 : 1;
  const float* pp = pre + (base + (size_t)t0) * GATES + g;
  const ptrdiff_t pstr = (ptrdiff_t)dt * GATES;

  float pf0 = pp[0], pf1 = pp[pstr], pf2 = pp[pstr * 2], pf3 = pp[pstr * 3];

#define LSTM_STEP(TK, PAR, PF)                                                 \
  do {                                                                         \
    float a0 = 0.f, a1 = 0.f, a2 = 0.f, a3 = 0.f;                              \
    const float4* h4 = (const float4*)&h_s[w][0];                              \
    _Pragma("unroll")                                                          \
    for (int kk = 0; kk < 16; ++kk) {                                          \
      const float4 hv = h4[kk];   /* wave-uniform addr: broadcast, no conflict */ \
      a0 = fmaf(hv.x, wv[kk].x, a0);                                           \
      a1 = fmaf(hv.y, wv[kk].y, a1);                                           \
      a2 = fmaf(hv.z, wv[kk].z, a2);                                           \
      a3 = fmaf(hv.w, wv[kk].w, a3);                                           \
    }                                                                          \
    const float z = ((a0 + a1) + (a2 + a3)) + (PF);                            \
    const float act = (w == 2) ? tanh_(z) : sigm(z);  /* wave-uniform branch */ \
    abuf[PAR][g] = act;                                                        \
    asm volatile("s_waitcnt lgkmcnt(0)\n\ts_barrier" ::: "memory");            \
    const float ig = abuf[PAR][j],           fg = abuf[PAR][HID + j];          \
    const float gg = abuf[PAR][2 * HID + j], og = abuf[PAR][3 * HID + j];      \
    c = fmaf(fg, c, ig * gg);                                                  \
    const float hv2 = og * tanh_(c);                                           \
    h_s[w][j] = hv2;                                                           \
    if (final_layer) sum += hv2;                                               \
    else if (w == 0)                                                           \
      hout[((size_t)b * TT + (size_t)(t0 + dt * (TK))) * (2 * HID) + d * HID + j] = hv2; \
  } while (0)

  for (int t = 0; t < TT; t += 4) {
    LSTM_STEP(t + 0, 0, pf0);
    { int ip = t + 4; if (ip >= TT) ip = 0; pf0 = pp[pstr * (ptrdiff_t)ip]; }
    LSTM_STEP(t + 1, 1, pf1);
    { int ip = t + 5; if (ip >= TT) ip = 0; pf1 = pp[pstr * (ptrdiff_t)ip]; }
    LSTM_STEP(t + 2, 0, pf2);
    { int ip = t + 6; if (ip >= TT) ip = 0; pf2 = pp[pstr * (ptrdiff_t)ip]; }
    LSTM_STEP(t + 3, 1, pf3);
    { int ip = t + 7; if (ip >= TT) ip = 0; pf3 = pp[pstr * (ptrdiff_t)ip]; }
  }
#undef LSTM_STEP

  if (final_layer && w == 0) out[b * (2 * HID) + d * HID + j] = sum * (1.0f / (float)TT);
}

// ---------- launch ----------
extern "C" void kernel_launch(void* const* d_in, const int* in_sizes, int n_in,
                              void* d_out, int out_size, void* d_ws, size_t ws_size,
                              hipStream_t stream) {
  const float* x         = (const float*)d_in[0];
  const float* binpoints = (const float*)d_in[1];
  const float* w_ih[3] = {(const float*)d_in[2], (const float*)d_in[6],  (const float*)d_in[10]};
  const float* w_hh[3] = {(const float*)d_in[3], (const float*)d_in[7],  (const float*)d_in[11]};
  const float* b_ih[3] = {(const float*)d_in[4], (const float*)d_in[8],  (const float*)d_in[12]};
  const float* b_hh[3] = {(const float*)d_in[5], (const float*)d_in[9],  (const float*)d_in[13]};
  float* out = (float*)d_out;

  // workspace layout (~349 MB):
  //   pre  : 2*MTOT*256 f32 = 262,144,000 B
  //   Hbuf : MTOT*128 f32   =  65,536,000 B
  //   h0   : MTOT*40 f32    =  20,480,000 B
  //   fbank: 40*257 f32, lohi: 80 i32
  float* pre   = (float*)d_ws;
  float* Hbuf  = pre  + (size_t)2 * MTOT * GATES;
  float* h0    = Hbuf + (size_t)MTOT * 128;
  float* fbank = h0   + (size_t)MTOT * NFILT;
  int*   lohi  = (int*)(fbank + NFILT * NBINS);

  k_fbank<<<1, 256, 0, stream>>>(binpoints, fbank, lohi);
  k_feat<<<MTOT, 64, 0, stream>>>(x, fbank, lohi, h0);

  // layer 0 (K=40)
  k_gemm<40, 40><<<dim3(MTOT / 128, GATES / 64, 2), 256, 0, stream>>>(h0, w_ih[0], b_ih[0], b_hh[0], pre);
  k_lstm4w<<<dim3(BB, 2), 256, 0, stream>>>(pre, w_hh[0], Hbuf, out, 0);

  // layer 1 (K=128)
  k_gemm<128, 32><<<dim3(MTOT / 128, GATES / 64, 2), 256, 0, stream>>>(Hbuf, w_ih[1], b_ih[1], b_hh[1], pre);
  k_lstm4w<<<dim3(BB, 2), 256, 0, stream>>>(pre, w_hh[1], Hbuf, out, 0);

  // layer 2 (K=128)
  k_gemm<128, 32><<<dim3(MTOT / 128, GATES / 64, 2), 256, 0, stream>>>(Hbuf, w_ih[2], b_ih[2], b_hh[2], pre);
  k_lstm4w<<<dim3(BB, 2), 256, 0, stream>>>(pre, w_hh[2], Hbuf, out, 1);
}